// Round 13
// baseline (3870.664 us; speedup 1.0000x reference)
//
#include <hip/hip_runtime.h>
#include <hip/hip_bf16.h>
#include <math.h>

typedef __attribute__((ext_vector_type(8))) short s16x8;
typedef __attribute__((ext_vector_type(4))) float f32x4;

#define T_TOK 16384
#define D_DIM 1024
#define F_DIM 2048
#define E_NUM 8
#define RCAP 34816  // 2*T + 8*256 worst-case 256-padded rows

__device__ __forceinline__ unsigned short f2b(float f) {
  unsigned u = __float_as_uint(f);
  u += 0x7fff + ((u >> 16) & 1);
  return (unsigned short)(u >> 16);
}
__device__ __forceinline__ unsigned pk2(float a, float b) {
  __hip_bfloat162 h = __float22bfloat162_rn(make_float2(a, b));
  return *reinterpret_cast<unsigned*>(&h);
}

// ---------------- weight cast fp32 -> bf16 ----------------
__global__ void castw_k(const float* __restrict__ w1, const float* __restrict__ w2,
                        unsigned short* __restrict__ w1b, unsigned short* __restrict__ w2b) {
  size_t i = ((size_t)blockIdx.x * 256 + threadIdx.x) * 4;
  float4 a = *(const float4*)(w1 + i);
  float4 b = *(const float4*)(w2 + i);
  uint2 ua, ub;
  ua.x = pk2(a.x, a.y); ua.y = pk2(a.z, a.w);
  ub.x = pk2(b.x, b.y); ub.y = pk2(b.z, b.w);
  *(uint2*)(w1b + i) = ua;
  *(uint2*)(w2b + i) = ub;
}

// ---------------- router (+ fused x->bf16 cast) ----------------
__global__ void router_k(const float* __restrict__ x, const float* __restrict__ wr,
                         int* __restrict__ topi, float* __restrict__ topw,
                         float* __restrict__ probs8, unsigned short* __restrict__ xb) {
  int tid = threadIdx.x, wid = tid >> 6, lane = tid & 63;
  int t = blockIdx.x * 4 + wid;
  const float* xr = x + (size_t)t * D_DIM;
  float4 xv[4];
#pragma unroll
  for (int i = 0; i < 4; ++i) xv[i] = *(const float4*)(xr + i * 256 + lane * 4);
#pragma unroll
  for (int i = 0; i < 4; ++i) {
    uint2 u; u.x = pk2(xv[i].x, xv[i].y); u.y = pk2(xv[i].z, xv[i].w);
    *(uint2*)(xb + (size_t)t * D_DIM + i * 256 + lane * 4) = u;
  }
  float logit[E_NUM];
#pragma unroll
  for (int e = 0; e < E_NUM; ++e) {
    const float* wrow = wr + e * D_DIM;
    float p = 0.f;
#pragma unroll
    for (int i = 0; i < 4; ++i) {
      float4 wv = *(const float4*)(wrow + i * 256 + lane * 4);
      p += xv[i].x * wv.x + xv[i].y * wv.y + xv[i].z * wv.z + xv[i].w * wv.w;
    }
    for (int s = 32; s; s >>= 1) p += __shfl_xor(p, s);
    logit[e] = p;
  }
  if (lane == 0) {
    float m = logit[0];
    for (int e = 1; e < E_NUM; ++e) m = fmaxf(m, logit[e]);
    float pr[E_NUM];
    float sum = 0.f;
    for (int e = 0; e < E_NUM; ++e) { pr[e] = expf(logit[e] - m); sum += pr[e]; }
    float inv = 1.f / sum;
    for (int e = 0; e < E_NUM; ++e) { pr[e] *= inv; probs8[t * 8 + e] = pr[e]; }
    int i0 = 0;
    for (int e = 1; e < E_NUM; ++e) if (pr[e] > pr[i0]) i0 = e;
    int i1 = (i0 == 0) ? 1 : 0;
    for (int e = 0; e < E_NUM; ++e) if (e != i0 && pr[e] > pr[i1]) i1 = e;
    float wsum = pr[i0] + pr[i1];
    topi[2 * t] = i0;  topi[2 * t + 1] = i1;
    topw[2 * t] = pr[i0] / wsum;  topw[2 * t + 1] = pr[i1] / wsum;
  }
}

// ---------------- histogram ----------------
__global__ void hist_k(const int* __restrict__ topi, const float* __restrict__ probs8,
                       int* __restrict__ cnt, float* __restrict__ usage) {
  __shared__ int sc[E_NUM];
  __shared__ float su[E_NUM];
  int tid = threadIdx.x;
  if (tid < E_NUM) { sc[tid] = 0; su[tid] = 0.f; }
  __syncthreads();
  for (int i = blockIdx.x * 256 + tid; i < 2 * T_TOK; i += 256 * 64)
    atomicAdd(&sc[topi[i]], 1);
  for (int i = blockIdx.x * 256 + tid; i < 8 * T_TOK; i += 256 * 64)
    atomicAdd(&su[i & 7], probs8[i]);
  __syncthreads();
  if (tid < E_NUM) { atomicAdd(&cnt[tid], sc[tid]); atomicAdd(&usage[tid], su[tid]); }
}

// ---------------- offsets (256-padded) + aux ----------------
__global__ void scan_k(const int* __restrict__ cnt, int* __restrict__ offs,
                       const float* __restrict__ usage, float* __restrict__ aux) {
  if (threadIdx.x == 0 && blockIdx.x == 0) {
    int o = 0;
    for (int e = 0; e < E_NUM; ++e) { offs[e] = o; o += (cnt[e] + 255) & ~255; }
    offs[E_NUM] = o;
    float s = 0.f;
    for (int e = 0; e < E_NUM; ++e) { float m = usage[e] * (1.f / T_TOK); s += m * m; }
    *aux = (float)E_NUM * s;
  }
}

// ---------------- assignment: pair -> row ----------------
__global__ void assign_k(const int* __restrict__ topi, const int* __restrict__ offs,
                         int* __restrict__ cur, int* __restrict__ rowpair) {
  int p = blockIdx.x * 256 + threadIdx.x;
  int lane = threadIdx.x & 63;
  int e = topi[p];
  int r = 0;
#pragma unroll
  for (int ee = 0; ee < E_NUM; ++ee) {
    unsigned long long mask = __ballot(e == ee);
    if (e == ee) {
      int leader = __ffsll((unsigned long long)mask) - 1;
      int rank = __popcll(mask & ((1ull << lane) - 1ull));
      int b = 0;
      if (lane == leader) b = atomicAdd(&cur[ee], (int)__popcll(mask));
      b = __shfl(b, leader);
      r = offs[ee] + b + rank;
    }
  }
  rowpair[r] = p;
}

// ====== reg-staged (T14) GEMM body: 128x128 tile, BK=64, 4 waves, 32KB LDS ======
// r9's proven 2-barrier loop. launch_bounds(256,5): 5 blocks/CU (LDS 5x32KB =
// 160KB exact), VGPR cap ~96 >= 84 used -> no spill, 20 waves/CU for TLP.

#define RGEMM_BODY(NT, EPILOGUE)                                               \
  f32x4 acc[4][4] = {};                                                        \
  s16x8 rA[4], rB[4];                                                          \
  _Pragma("unroll") for (int i = 0; i < 4; ++i) {                              \
    rA[i] = *(const s16x8*)(pA[i]);                                            \
    rB[i] = *(const s16x8*)(pB[i]);                                            \
  }                                                                            \
  _Pragma("unroll 2")                                                          \
  for (int t = 0; t < NT; ++t) {                                               \
    if (t) __syncthreads();                                                    \
    _Pragma("unroll") for (int i = 0; i < 4; ++i) {                            \
      *(s16x8*)&As[wo[i]] = rA[i];                                             \
      *(s16x8*)&Bs[wo[i]] = rB[i];                                             \
    }                                                                          \
    __syncthreads();                                                           \
    if (t < NT - 1) {                                                          \
      int k0 = (t + 1) * 64;                                                   \
      _Pragma("unroll") for (int i = 0; i < 4; ++i) {                          \
        rA[i] = *(const s16x8*)(pA[i] + k0);                                   \
        rB[i] = *(const s16x8*)(pB[i] + k0);                                   \
      }                                                                        \
    }                                                                          \
    int ar = wm * 64 + rl, br = wn * 64 + rl;                                  \
    _Pragma("unroll") for (int kk = 0; kk < 2; ++kk) {                         \
      int cs = (((kk * 4 + g4) ^ (rl & 7)) << 3);                              \
      s16x8 a[4], b[4];                                                        \
      _Pragma("unroll") for (int m = 0; m < 4; ++m)                            \
        a[m] = *(const s16x8*)&As[(ar + m * 16) * 64 + cs];                    \
      _Pragma("unroll") for (int n = 0; n < 4; ++n)                            \
        b[n] = *(const s16x8*)&Bs[(br + n * 16) * 64 + cs];                    \
      __builtin_amdgcn_s_setprio(1);                                           \
      _Pragma("unroll") for (int m = 0; m < 4; ++m)                            \
        _Pragma("unroll") for (int n = 0; n < 4; ++n)                          \
          acc[m][n] = __builtin_amdgcn_mfma_f32_16x16x32_bf16(                 \
              a[m], b[n], acc[m][n], 0, 0, 0);                                 \
      __builtin_amdgcn_s_setprio(0);                                           \
    }                                                                          \
  }                                                                            \
  EPILOGUE

// ---------------- GEMM1: hseg = gelu(gather(xb) @ w1[e]^T) ----------------
__global__ __launch_bounds__(256, 5) void gemm1v_k(
    const unsigned short* __restrict__ xb, const unsigned short* __restrict__ w1b,
    const int* __restrict__ offs, const int* __restrict__ rowpair,
    const unsigned short* __restrict__ zrow,
    unsigned short* __restrict__ hseg, int segbase, int segrows) {
  int bid0 = blockIdx.x;
  int bid = ((bid0 & 7) << 11) | (bid0 >> 3);  // chunk swizzle (grid 16384)
  int e = bid >> 11, rem = bid & 2047, mt = rem >> 4, nt = rem & 15;
  int rend = offs[e + 1];
  int rowbase = offs[e] + mt * 128;
  if (rowbase >= rend || rowbase < segbase || rowbase >= segbase + segrows) return;

  __shared__ short As[128 * 64];
  __shared__ short Bs[128 * 64];
  int tid = threadIdx.x, wid = tid >> 6, lane = tid & 63;
  int wm = wid >> 1, wn = wid & 1, rl = lane & 15, g4 = lane >> 4;
  int j7 = tid & 7, rr = tid >> 3;  // rr 0..31
  int wg = ((j7 ^ (rr & 7)) << 3);
  int wo[4];
#pragma unroll
  for (int i = 0; i < 4; ++i) wo[i] = (rr + i * 32) * 64 + wg;

  const unsigned short* pA[4];
  const unsigned short* pB[4];
#pragma unroll
  for (int i = 0; i < 4; ++i) {
    int p = rowpair[rowbase + rr + i * 32];
    pA[i] = (p >= 0 ? xb + (size_t)(p >> 1) * D_DIM : zrow) + j7 * 8;
    pB[i] = w1b + ((size_t)e * F_DIM + nt * 128 + rr + i * 32) * D_DIM + j7 * 8;
  }

  RGEMM_BODY(16, {
    size_t rloc = (size_t)(rowbase - segbase);
    int c0 = nt * 128 + wn * 64 + rl;
    int lr0 = wm * 64 + (g4 << 2);
    _Pragma("unroll") for (int m = 0; m < 4; ++m)
      _Pragma("unroll") for (int j = 0; j < 4; ++j) {
        size_t rrow = (rloc + lr0 + m * 16 + j) * F_DIM;
        _Pragma("unroll") for (int n = 0; n < 4; ++n) {
          float v = acc[m][n][j];
          float g = 0.5f * v * (1.f + erff(v * 0.70710678118f));
          hseg[rrow + c0 + n * 16] = f2b(g);
        }
      }
  })
}

// ---------------- GEMM2: out[t] += w * (hseg @ w2[e]^T), atomic scatter ----------------
__global__ __launch_bounds__(256, 5) void gemm2v_k(
    const unsigned short* __restrict__ hseg, const unsigned short* __restrict__ w2b,
    const int* __restrict__ offs, const int* __restrict__ rowpair,
    const float* __restrict__ topw, float* __restrict__ out,
    int segbase, int segrows) {
  int bid0 = blockIdx.x;
  int bid = ((bid0 & 7) << 10) | (bid0 >> 3);  // chunk swizzle (grid 8192)
  int e = bid >> 10, rem = bid & 1023, mt = rem >> 3, nt = rem & 7;
  int rend = offs[e + 1];
  int rowbase = offs[e] + mt * 128;
  if (rowbase >= rend || rowbase < segbase || rowbase >= segbase + segrows) return;

  __shared__ short As[128 * 64];
  __shared__ short Bs[128 * 64];
  int tid = threadIdx.x, wid = tid >> 6, lane = tid & 63;
  int wm = wid >> 1, wn = wid & 1, rl = lane & 15, g4 = lane >> 4;
  int j7 = tid & 7, rr = tid >> 3;
  int wg = ((j7 ^ (rr & 7)) << 3);
  int wo[4];
#pragma unroll
  for (int i = 0; i < 4; ++i) wo[i] = (rr + i * 32) * 64 + wg;

  size_t rloc = (size_t)(rowbase - segbase);
  const unsigned short* pA[4];
  const unsigned short* pB[4];
#pragma unroll
  for (int i = 0; i < 4; ++i) {
    pA[i] = hseg + (rloc + rr + i * 32) * F_DIM + j7 * 8;
    pB[i] = w2b + ((size_t)e * D_DIM + nt * 128 + rr + i * 32) * F_DIM + j7 * 8;
  }

  RGEMM_BODY(32, {
    int c0 = nt * 128 + wn * 64 + rl;
    int lr0 = wm * 64 + (g4 << 2);
    _Pragma("unroll") for (int m = 0; m < 4; ++m)
      _Pragma("unroll") for (int j = 0; j < 4; ++j) {
        int lr = lr0 + m * 16 + j;
        int p = rowpair[rowbase + lr];
        if (p >= 0) {
          float wgt = topw[p];
          float* op = out + (size_t)(p >> 1) * D_DIM + c0;
          _Pragma("unroll") for (int n = 0; n < 4; ++n)
            unsafeAtomicAdd(op + n * 16, wgt * acc[m][n][j]);
        }
      }
  })
}

extern "C" void kernel_launch(void* const* d_in, const int* in_sizes, int n_in,
                              void* d_out, int out_size, void* d_ws, size_t ws_size,
                              hipStream_t stream) {
  const float* x  = (const float*)d_in[0];
  const float* wr = (const float*)d_in[1];
  const float* w1 = (const float*)d_in[2];
  const float* w2 = (const float*)d_in[3];
  float* out = (float*)d_out;

  char* ws = (char*)d_ws;
  int* cnt   = (int*)ws;               // [8]
  int* cur   = cnt + 8;                // [8]
  int* offs  = cnt + 16;               // [9]
  float* usage = (float*)(cnt + 25);   // [8]
  unsigned short* zrow = (unsigned short*)(ws + 4096);  // 2KB zeros (= D_DIM bf16)
  size_t off = 8192;
  int*   topi = (int*)(ws + off);     off += (size_t)2 * T_TOK * 4;
  float* topw = (float*)(ws + off);   off += (size_t)2 * T_TOK * 4;
  int*   rowpair = (int*)(ws + off);  off += (size_t)RCAP * 4;
  float* probs8 = (float*)(ws + off); off += (size_t)T_TOK * 8 * 4;
  off = (off + 255) & ~(size_t)255;

  unsigned short* xb = (unsigned short*)(ws + off);
  off += (size_t)T_TOK * D_DIM * 2;                       // 33.6 MB
  unsigned short* w1b = (unsigned short*)(ws + off);
  off += (size_t)E_NUM * F_DIM * D_DIM * 2;               // 33.6 MB
  unsigned short* w2b = (unsigned short*)(ws + off);
  off += (size_t)E_NUM * F_DIM * D_DIM * 2;               // 33.6 MB
  if (ws_size < off + (size_t)4096 * F_DIM * 2) return;   // need >= 16.8MB hseg
  size_t avail = ws_size - off;
  size_t segcap = (avail / ((size_t)F_DIM * 2)) & ~(size_t)255;
  int segrows = segcap > (size_t)RCAP ? RCAP : (int)segcap;
  unsigned short* hseg = (unsigned short*)(ws + off);
  int nseg = (RCAP + segrows - 1) / segrows;

  hipMemsetAsync(ws, 0, 8192, stream);
  hipMemsetAsync(rowpair, 0xFF, (size_t)RCAP * 4, stream);
  hipMemsetAsync(d_out, 0, (size_t)out_size * 4, stream);
  castw_k<<<16384, 256, 0, stream>>>(w1, w2, w1b, w2b);
  router_k<<<T_TOK / 4, 256, 0, stream>>>(x, wr, topi, topw, probs8, xb);
  hist_k<<<64, 256, 0, stream>>>(topi, probs8, cnt, usage);
  scan_k<<<1, 64, 0, stream>>>(cnt, offs, usage, out + (size_t)T_TOK * D_DIM);
  assign_k<<<2 * T_TOK / 256, 256, 0, stream>>>(topi, offs, cur, rowpair);

  for (int s = 0; s < nseg; ++s) {
    int segbase = s * segrows;
    gemm1v_k<<<16384, 256, 0, stream>>>(xb, w1b, offs, rowpair, zrow, hseg, segbase, segrows);
    gemm2v_k<<<8192, 256, 0, stream>>>(hseg, w2b, offs, rowpair, topw, out, segbase, segrows);
  }
}

// Round 14
// 519.797 us; speedup vs baseline: 7.4465x; 7.4465x over previous
//
#include <hip/hip_runtime.h>
#include <hip/hip_bf16.h>
#include <math.h>

typedef __attribute__((ext_vector_type(8))) short s16x8;
typedef __attribute__((ext_vector_type(4))) float f32x4;

#define T_TOK 16384
#define D_DIM 1024
#define F_DIM 2048
#define E_NUM 8
#define RCAP 34816  // 2*T + 8*256 worst-case 256-padded rows

__device__ __forceinline__ unsigned short f2b(float f) {
  unsigned u = __float_as_uint(f);
  u += 0x7fff + ((u >> 16) & 1);
  return (unsigned short)(u >> 16);
}
__device__ __forceinline__ float b2f(unsigned short h) {
  return __uint_as_float(((unsigned)h) << 16);
}
__device__ __forceinline__ unsigned pk2(float a, float b) {
  __hip_bfloat162 h = __float22bfloat162_rn(make_float2(a, b));
  return *reinterpret_cast<unsigned*>(&h);
}

// ---------------- weight cast fp32 -> bf16 ----------------
__global__ void castw_k(const float* __restrict__ w1, const float* __restrict__ w2,
                        unsigned short* __restrict__ w1b, unsigned short* __restrict__ w2b) {
  size_t i = ((size_t)blockIdx.x * 256 + threadIdx.x) * 4;
  float4 a = *(const float4*)(w1 + i);
  float4 b = *(const float4*)(w2 + i);
  uint2 ua, ub;
  ua.x = pk2(a.x, a.y); ua.y = pk2(a.z, a.w);
  ub.x = pk2(b.x, b.y); ub.y = pk2(b.z, b.w);
  *(uint2*)(w1b + i) = ua;
  *(uint2*)(w2b + i) = ub;
}

// ---------------- router (+ fused x->bf16 cast) ----------------
__global__ void router_k(const float* __restrict__ x, const float* __restrict__ wr,
                         int* __restrict__ topi, float* __restrict__ topw,
                         float* __restrict__ probs8, unsigned short* __restrict__ xb) {
  int tid = threadIdx.x, wid = tid >> 6, lane = tid & 63;
  int t = blockIdx.x * 4 + wid;
  const float* xr = x + (size_t)t * D_DIM;
  float4 xv[4];
#pragma unroll
  for (int i = 0; i < 4; ++i) xv[i] = *(const float4*)(xr + i * 256 + lane * 4);
#pragma unroll
  for (int i = 0; i < 4; ++i) {
    uint2 u; u.x = pk2(xv[i].x, xv[i].y); u.y = pk2(xv[i].z, xv[i].w);
    *(uint2*)(xb + (size_t)t * D_DIM + i * 256 + lane * 4) = u;
  }
  float logit[E_NUM];
#pragma unroll
  for (int e = 0; e < E_NUM; ++e) {
    const float* wrow = wr + e * D_DIM;
    float p = 0.f;
#pragma unroll
    for (int i = 0; i < 4; ++i) {
      float4 wv = *(const float4*)(wrow + i * 256 + lane * 4);
      p += xv[i].x * wv.x + xv[i].y * wv.y + xv[i].z * wv.z + xv[i].w * wv.w;
    }
    for (int s = 32; s; s >>= 1) p += __shfl_xor(p, s);
    logit[e] = p;
  }
  if (lane == 0) {
    float m = logit[0];
    for (int e = 1; e < E_NUM; ++e) m = fmaxf(m, logit[e]);
    float pr[E_NUM];
    float sum = 0.f;
    for (int e = 0; e < E_NUM; ++e) { pr[e] = expf(logit[e] - m); sum += pr[e]; }
    float inv = 1.f / sum;
    for (int e = 0; e < E_NUM; ++e) { pr[e] *= inv; probs8[t * 8 + e] = pr[e]; }
    int i0 = 0;
    for (int e = 1; e < E_NUM; ++e) if (pr[e] > pr[i0]) i0 = e;
    int i1 = (i0 == 0) ? 1 : 0;
    for (int e = 0; e < E_NUM; ++e) if (e != i0 && pr[e] > pr[i1]) i1 = e;
    float wsum = pr[i0] + pr[i1];
    topi[2 * t] = i0;  topi[2 * t + 1] = i1;
    topw[2 * t] = pr[i0] / wsum;  topw[2 * t + 1] = pr[i1] / wsum;
  }
}

// ---------------- histogram ----------------
__global__ void hist_k(const int* __restrict__ topi, const float* __restrict__ probs8,
                       int* __restrict__ cnt, float* __restrict__ usage) {
  __shared__ int sc[E_NUM];
  __shared__ float su[E_NUM];
  int tid = threadIdx.x;
  if (tid < E_NUM) { sc[tid] = 0; su[tid] = 0.f; }
  __syncthreads();
  for (int i = blockIdx.x * 256 + tid; i < 2 * T_TOK; i += 256 * 64)
    atomicAdd(&sc[topi[i]], 1);
  for (int i = blockIdx.x * 256 + tid; i < 8 * T_TOK; i += 256 * 64)
    atomicAdd(&su[i & 7], probs8[i]);
  __syncthreads();
  if (tid < E_NUM) { atomicAdd(&cnt[tid], sc[tid]); atomicAdd(&usage[tid], su[tid]); }
}

// ---------------- offsets (256-padded) + aux ----------------
__global__ void scan_k(const int* __restrict__ cnt, int* __restrict__ offs,
                       const float* __restrict__ usage, float* __restrict__ aux) {
  if (threadIdx.x == 0 && blockIdx.x == 0) {
    int o = 0;
    for (int e = 0; e < E_NUM; ++e) { offs[e] = o; o += (cnt[e] + 255) & ~255; }
    offs[E_NUM] = o;
    float s = 0.f;
    for (int e = 0; e < E_NUM; ++e) { float m = usage[e] * (1.f / T_TOK); s += m * m; }
    *aux = (float)E_NUM * s;
  }
}

// ---------------- assignment: pair -> row ----------------
__global__ void assign_k(const int* __restrict__ topi, const int* __restrict__ offs,
                         int* __restrict__ cur, int* __restrict__ rowpair) {
  int p = blockIdx.x * 256 + threadIdx.x;
  int lane = threadIdx.x & 63;
  int e = topi[p];
  int r = 0;
#pragma unroll
  for (int ee = 0; ee < E_NUM; ++ee) {
    unsigned long long mask = __ballot(e == ee);
    if (e == ee) {
      int leader = __ffsll((unsigned long long)mask) - 1;
      int rank = __popcll(mask & ((1ull << lane) - 1ull));
      int b = 0;
      if (lane == leader) b = atomicAdd(&cur[ee], (int)__popcll(mask));
      b = __shfl(b, leader);
      r = offs[ee] + b + rank;
    }
  }
  rowpair[r] = p;
}

// ====== reg-staged (T14) GEMM body: 128x128 tile, BK=64, 4 waves, 32KB LDS ======
// r9's proven 2-barrier loop; launch_bounds(256,3) -> 84 VGPR, no spill (verified).

#define RGEMM_BODY(NT, EPILOGUE)                                               \
  f32x4 acc[4][4] = {};                                                        \
  s16x8 rA[4], rB[4];                                                          \
  _Pragma("unroll") for (int i = 0; i < 4; ++i) {                              \
    rA[i] = *(const s16x8*)(pA[i]);                                            \
    rB[i] = *(const s16x8*)(pB[i]);                                            \
  }                                                                            \
  _Pragma("unroll 2")                                                          \
  for (int t = 0; t < NT; ++t) {                                               \
    if (t) __syncthreads();                                                    \
    _Pragma("unroll") for (int i = 0; i < 4; ++i) {                            \
      *(s16x8*)&As[wo[i]] = rA[i];                                             \
      *(s16x8*)&Bs[wo[i]] = rB[i];                                             \
    }                                                                          \
    __syncthreads();                                                           \
    if (t < NT - 1) {                                                          \
      int k0 = (t + 1) * 64;                                                   \
      _Pragma("unroll") for (int i = 0; i < 4; ++i) {                          \
        rA[i] = *(const s16x8*)(pA[i] + k0);                                   \
        rB[i] = *(const s16x8*)(pB[i] + k0);                                   \
      }                                                                        \
    }                                                                          \
    int ar = wm * 64 + rl, br = wn * 64 + rl;                                  \
    _Pragma("unroll") for (int kk = 0; kk < 2; ++kk) {                         \
      int cs = (((kk * 4 + g4) ^ (rl & 7)) << 3);                              \
      s16x8 a[4], b[4];                                                        \
      _Pragma("unroll") for (int m = 0; m < 4; ++m)                            \
        a[m] = *(const s16x8*)&As[(ar + m * 16) * 64 + cs];                    \
      _Pragma("unroll") for (int n = 0; n < 4; ++n)                            \
        b[n] = *(const s16x8*)&Bs[(br + n * 16) * 64 + cs];                    \
      __builtin_amdgcn_s_setprio(1);                                           \
      _Pragma("unroll") for (int m = 0; m < 4; ++m)                            \
        _Pragma("unroll") for (int n = 0; n < 4; ++n)                          \
          acc[m][n] = __builtin_amdgcn_mfma_f32_16x16x32_bf16(                 \
              a[m], b[n], acc[m][n], 0, 0, 0);                                 \
      __builtin_amdgcn_s_setprio(0);                                           \
    }                                                                          \
  }                                                                            \
  EPILOGUE

// ---------------- GEMM1: hseg = gelu(gather(xb) @ w1[e]^T) ----------------
__global__ __launch_bounds__(256, 3) void gemm1v_k(
    const unsigned short* __restrict__ xb, const unsigned short* __restrict__ w1b,
    const int* __restrict__ offs, const int* __restrict__ rowpair,
    const unsigned short* __restrict__ zrow,
    unsigned short* __restrict__ hseg, int segbase, int segrows) {
  int bid0 = blockIdx.x;
  int bid = ((bid0 & 7) << 11) | (bid0 >> 3);  // chunk swizzle (grid 16384)
  int e = bid >> 11, rem = bid & 2047, mt = rem >> 4, nt = rem & 15;
  int rend = offs[e + 1];
  int rowbase = offs[e] + mt * 128;
  if (rowbase >= rend || rowbase < segbase || rowbase >= segbase + segrows) return;

  __shared__ short As[128 * 64];
  __shared__ short Bs[128 * 64];
  int tid = threadIdx.x, wid = tid >> 6, lane = tid & 63;
  int wm = wid >> 1, wn = wid & 1, rl = lane & 15, g4 = lane >> 4;
  int j7 = tid & 7, rr = tid >> 3;  // rr 0..31
  int wg = ((j7 ^ (rr & 7)) << 3);
  int wo[4];
#pragma unroll
  for (int i = 0; i < 4; ++i) wo[i] = (rr + i * 32) * 64 + wg;

  const unsigned short* pA[4];
  const unsigned short* pB[4];
#pragma unroll
  for (int i = 0; i < 4; ++i) {
    int p = rowpair[rowbase + rr + i * 32];
    pA[i] = (p >= 0 ? xb + (size_t)(p >> 1) * D_DIM : zrow) + j7 * 8;
    pB[i] = w1b + ((size_t)e * F_DIM + nt * 128 + rr + i * 32) * D_DIM + j7 * 8;
  }

  RGEMM_BODY(16, {
    size_t rloc = (size_t)(rowbase - segbase);
    int c0 = nt * 128 + wn * 64 + rl;
    int lr0 = wm * 64 + (g4 << 2);
    _Pragma("unroll") for (int m = 0; m < 4; ++m)
      _Pragma("unroll") for (int j = 0; j < 4; ++j) {
        size_t rrow = (rloc + lr0 + m * 16 + j) * F_DIM;
        _Pragma("unroll") for (int n = 0; n < 4; ++n) {
          float v = acc[m][n][j];
          float g = 0.5f * v * (1.f + erff(v * 0.70710678118f));
          hseg[rrow + c0 + n * 16] = f2b(g);
        }
      }
  })
}

// ---------------- GEMM2 (store path): obuf[pair] = hseg @ w2[e]^T ----------------
__global__ __launch_bounds__(256, 3) void gemm2s_k(
    const unsigned short* __restrict__ hseg, const unsigned short* __restrict__ w2b,
    const int* __restrict__ offs, const int* __restrict__ rowpair,
    unsigned short* __restrict__ obuf, int segbase, int segrows) {
  int bid0 = blockIdx.x;
  int bid = ((bid0 & 7) << 10) | (bid0 >> 3);  // chunk swizzle (grid 8192)
  int e = bid >> 10, rem = bid & 1023, mt = rem >> 3, nt = rem & 7;
  int rend = offs[e + 1];
  int rowbase = offs[e] + mt * 128;
  if (rowbase >= rend || rowbase < segbase || rowbase >= segbase + segrows) return;

  __shared__ short As[128 * 64];
  __shared__ short Bs[128 * 64];
  int tid = threadIdx.x, wid = tid >> 6, lane = tid & 63;
  int wm = wid >> 1, wn = wid & 1, rl = lane & 15, g4 = lane >> 4;
  int j7 = tid & 7, rr = tid >> 3;
  int wg = ((j7 ^ (rr & 7)) << 3);
  int wo[4];
#pragma unroll
  for (int i = 0; i < 4; ++i) wo[i] = (rr + i * 32) * 64 + wg;

  size_t rloc = (size_t)(rowbase - segbase);
  const unsigned short* pA[4];
  const unsigned short* pB[4];
#pragma unroll
  for (int i = 0; i < 4; ++i) {
    pA[i] = hseg + (rloc + rr + i * 32) * F_DIM + j7 * 8;
    pB[i] = w2b + ((size_t)e * D_DIM + nt * 128 + rr + i * 32) * F_DIM + j7 * 8;
  }

  RGEMM_BODY(32, {
    int c0 = nt * 128 + wn * 64 + rl;
    int lr0 = wm * 64 + (g4 << 2);
    _Pragma("unroll") for (int m = 0; m < 4; ++m)
      _Pragma("unroll") for (int j = 0; j < 4; ++j) {
        int lr = lr0 + m * 16 + j;
        int p = rowpair[rowbase + lr];
        if (p >= 0) {
          unsigned short* op = obuf + (size_t)p * D_DIM + c0;
          _Pragma("unroll") for (int n = 0; n < 4; ++n)
            op[n * 16] = f2b(acc[m][n][j]);
        }
      }
  })
}

// ---------------- GEMM2 (atomic fallback, nseg>1) ----------------
__global__ __launch_bounds__(256, 3) void gemm2v_k(
    const unsigned short* __restrict__ hseg, const unsigned short* __restrict__ w2b,
    const int* __restrict__ offs, const int* __restrict__ rowpair,
    const float* __restrict__ topw, float* __restrict__ out,
    int segbase, int segrows) {
  int bid0 = blockIdx.x;
  int bid = ((bid0 & 7) << 10) | (bid0 >> 3);
  int e = bid >> 10, rem = bid & 1023, mt = rem >> 3, nt = rem & 7;
  int rend = offs[e + 1];
  int rowbase = offs[e] + mt * 128;
  if (rowbase >= rend || rowbase < segbase || rowbase >= segbase + segrows) return;

  __shared__ short As[128 * 64];
  __shared__ short Bs[128 * 64];
  int tid = threadIdx.x, wid = tid >> 6, lane = tid & 63;
  int wm = wid >> 1, wn = wid & 1, rl = lane & 15, g4 = lane >> 4;
  int j7 = tid & 7, rr = tid >> 3;
  int wg = ((j7 ^ (rr & 7)) << 3);
  int wo[4];
#pragma unroll
  for (int i = 0; i < 4; ++i) wo[i] = (rr + i * 32) * 64 + wg;

  size_t rloc = (size_t)(rowbase - segbase);
  const unsigned short* pA[4];
  const unsigned short* pB[4];
#pragma unroll
  for (int i = 0; i < 4; ++i) {
    pA[i] = hseg + (rloc + rr + i * 32) * F_DIM + j7 * 8;
    pB[i] = w2b + ((size_t)e * D_DIM + nt * 128 + rr + i * 32) * F_DIM + j7 * 8;
  }

  RGEMM_BODY(32, {
    int c0 = nt * 128 + wn * 64 + rl;
    int lr0 = wm * 64 + (g4 << 2);
    _Pragma("unroll") for (int m = 0; m < 4; ++m)
      _Pragma("unroll") for (int j = 0; j < 4; ++j) {
        int lr = lr0 + m * 16 + j;
        int p = rowpair[rowbase + lr];
        if (p >= 0) {
          float wgt = topw[p];
          float* op = out + (size_t)(p >> 1) * D_DIM + c0;
          _Pragma("unroll") for (int n = 0; n < 4; ++n)
            unsafeAtomicAdd(op + n * 16, wgt * acc[m][n][j]);
        }
      }
  })
}

// ---------------- combine: out[t] = w0*obuf[2t] + w1*obuf[2t+1] ----------------
__global__ void combine_k(const unsigned short* __restrict__ obuf,
                          const float* __restrict__ topw, float* __restrict__ out) {
  int u = blockIdx.x * 256 + threadIdx.x;
  int t = u >> 7;
  int d0 = (u & 127) * 8;
  float w0 = topw[2 * t], w1 = topw[2 * t + 1];
  s16x8 a = *(const s16x8*)(obuf + (size_t)(2 * t) * D_DIM + d0);
  s16x8 b = *(const s16x8*)(obuf + (size_t)(2 * t + 1) * D_DIM + d0);
  float r[8];
#pragma unroll
  for (int j = 0; j < 8; ++j)
    r[j] = w0 * b2f((unsigned short)a[j]) + w1 * b2f((unsigned short)b[j]);
  float4 lo = {r[0], r[1], r[2], r[3]};
  float4 hi = {r[4], r[5], r[6], r[7]};
  float* o = out + (size_t)t * D_DIM + d0;
  *(float4*)o = lo;
  *(float4*)(o + 4) = hi;
}

extern "C" void kernel_launch(void* const* d_in, const int* in_sizes, int n_in,
                              void* d_out, int out_size, void* d_ws, size_t ws_size,
                              hipStream_t stream) {
  const float* x  = (const float*)d_in[0];
  const float* wr = (const float*)d_in[1];
  const float* w1 = (const float*)d_in[2];
  const float* w2 = (const float*)d_in[3];
  float* out = (float*)d_out;

  char* ws = (char*)d_ws;
  int* cnt   = (int*)ws;               // [8]
  int* cur   = cnt + 8;                // [8]
  int* offs  = cnt + 16;               // [9]
  float* usage = (float*)(cnt + 25);   // [8]
  unsigned short* zrow = (unsigned short*)(ws + 4096);  // 2KB zeros (= D_DIM bf16)
  size_t off = 8192;
  int*   topi = (int*)(ws + off);     off += (size_t)2 * T_TOK * 4;
  float* topw = (float*)(ws + off);   off += (size_t)2 * T_TOK * 4;
  int*   rowpair = (int*)(ws + off);  off += (size_t)RCAP * 4;
  float* probs8 = (float*)(ws + off); off += (size_t)T_TOK * 8 * 4;
  off = (off + 255) & ~(size_t)255;

  unsigned short* xb = (unsigned short*)(ws + off);
  off += (size_t)T_TOK * D_DIM * 2;                       // 33.6 MB
  unsigned short* w1b = (unsigned short*)(ws + off);
  off += (size_t)E_NUM * F_DIM * D_DIM * 2;               // 33.6 MB
  unsigned short* w2b = (unsigned short*)(ws + off);
  off += (size_t)E_NUM * F_DIM * D_DIM * 2;               // 33.6 MB
  if (ws_size < off + (size_t)4096 * F_DIM * 2) return;   // need >= 16.8MB hseg
  size_t avail = ws_size - off;
  size_t segcap = (avail / ((size_t)F_DIM * 2)) & ~(size_t)255;
  int segrows = segcap > (size_t)RCAP ? RCAP : (int)segcap;
  unsigned short* hseg = (unsigned short*)(ws + off);
  int nseg = (RCAP + segrows - 1) / segrows;

  // Store path: obuf[pair] (2*T rows, 67.1MB) aliases xb+w1b (67.2MB) — safe
  // only when nseg==1 (gemm1 fully done with xb/w1b before gemm2 writes).
  bool storepath = (nseg == 1);
  unsigned short* obuf = xb;

  hipMemsetAsync(ws, 0, 8192, stream);
  hipMemsetAsync(rowpair, 0xFF, (size_t)RCAP * 4, stream);
  if (!storepath) hipMemsetAsync(d_out, 0, (size_t)out_size * 4, stream);
  castw_k<<<16384, 256, 0, stream>>>(w1, w2, w1b, w2b);
  router_k<<<T_TOK / 4, 256, 0, stream>>>(x, wr, topi, topw, probs8, xb);
  hist_k<<<64, 256, 0, stream>>>(topi, probs8, cnt, usage);
  scan_k<<<1, 64, 0, stream>>>(cnt, offs, usage, out + (size_t)T_TOK * D_DIM);
  assign_k<<<2 * T_TOK / 256, 256, 0, stream>>>(topi, offs, cur, rowpair);

  for (int s = 0; s < nseg; ++s) {
    int segbase = s * segrows;
    gemm1v_k<<<16384, 256, 0, stream>>>(xb, w1b, offs, rowpair, zrow, hseg, segbase, segrows);
    if (storepath)
      gemm2s_k<<<8192, 256, 0, stream>>>(hseg, w2b, offs, rowpair, obuf, segbase, segrows);
    else
      gemm2v_k<<<8192, 256, 0, stream>>>(hseg, w2b, offs, rowpair, topw, out, segbase, segrows);
  }
  if (storepath)
    combine_k<<<T_TOK * D_DIM / 8 / 256, 256, 0, stream>>>(obuf, topw, out);
}

// Round 15
// 500.751 us; speedup vs baseline: 7.7297x; 1.0380x over previous
//
#include <hip/hip_runtime.h>
#include <hip/hip_bf16.h>
#include <math.h>

typedef __attribute__((ext_vector_type(8))) short s16x8;
typedef __attribute__((ext_vector_type(4))) float f32x4;

#define T_TOK 16384
#define D_DIM 1024
#define F_DIM 2048
#define E_NUM 8
#define RCAP 34816  // 2*T + 8*256 worst-case 256-padded rows

__device__ __forceinline__ unsigned short f2b(float f) {
  unsigned u = __float_as_uint(f);
  u += 0x7fff + ((u >> 16) & 1);
  return (unsigned short)(u >> 16);
}
__device__ __forceinline__ float b2f(unsigned short h) {
  return __uint_as_float(((unsigned)h) << 16);
}
__device__ __forceinline__ unsigned pk2(float a, float b) {
  __hip_bfloat162 h = __float22bfloat162_rn(make_float2(a, b));
  return *reinterpret_cast<unsigned*>(&h);
}
// Exact-GELU via branchless A&S 7.1.26 erf (|eps|<=1.5e-7 << bf16 ulp).
__device__ __forceinline__ float gelu_f(float v) {
  float x = v * 0.70710678118f;
  float ax = fabsf(x);
  float t = __builtin_amdgcn_rcpf(1.f + 0.3275911f * ax);
  float y = t * (0.254829592f +
           t * (-0.284496736f +
           t * (1.421413741f +
           t * (-1.453152027f +
           t * 1.061405429f))));
  float e = __expf(-x * x);
  float er = 1.f - y * e;
  er = (x < 0.f) ? -er : er;
  return 0.5f * v * (1.f + er);
}

// ---------------- weight cast fp32 -> bf16 ----------------
__global__ void castw_k(const float* __restrict__ w1, const float* __restrict__ w2,
                        unsigned short* __restrict__ w1b, unsigned short* __restrict__ w2b) {
  size_t i = ((size_t)blockIdx.x * 256 + threadIdx.x) * 4;
  float4 a = *(const float4*)(w1 + i);
  float4 b = *(const float4*)(w2 + i);
  uint2 ua, ub;
  ua.x = pk2(a.x, a.y); ua.y = pk2(a.z, a.w);
  ub.x = pk2(b.x, b.y); ub.y = pk2(b.z, b.w);
  *(uint2*)(w1b + i) = ua;
  *(uint2*)(w2b + i) = ub;
}

// ---------------- router (+ fused x->bf16 cast) ----------------
__global__ void router_k(const float* __restrict__ x, const float* __restrict__ wr,
                         int* __restrict__ topi, float* __restrict__ topw,
                         float* __restrict__ probs8, unsigned short* __restrict__ xb) {
  int tid = threadIdx.x, wid = tid >> 6, lane = tid & 63;
  int t = blockIdx.x * 4 + wid;
  const float* xr = x + (size_t)t * D_DIM;
  float4 xv[4];
#pragma unroll
  for (int i = 0; i < 4; ++i) xv[i] = *(const float4*)(xr + i * 256 + lane * 4);
#pragma unroll
  for (int i = 0; i < 4; ++i) {
    uint2 u; u.x = pk2(xv[i].x, xv[i].y); u.y = pk2(xv[i].z, xv[i].w);
    *(uint2*)(xb + (size_t)t * D_DIM + i * 256 + lane * 4) = u;
  }
  float logit[E_NUM];
#pragma unroll
  for (int e = 0; e < E_NUM; ++e) {
    const float* wrow = wr + e * D_DIM;
    float p = 0.f;
#pragma unroll
    for (int i = 0; i < 4; ++i) {
      float4 wv = *(const float4*)(wrow + i * 256 + lane * 4);
      p += xv[i].x * wv.x + xv[i].y * wv.y + xv[i].z * wv.z + xv[i].w * wv.w;
    }
    for (int s = 32; s; s >>= 1) p += __shfl_xor(p, s);
    logit[e] = p;
  }
  if (lane == 0) {
    float m = logit[0];
    for (int e = 1; e < E_NUM; ++e) m = fmaxf(m, logit[e]);
    float pr[E_NUM];
    float sum = 0.f;
    for (int e = 0; e < E_NUM; ++e) { pr[e] = expf(logit[e] - m); sum += pr[e]; }
    float inv = 1.f / sum;
    for (int e = 0; e < E_NUM; ++e) { pr[e] *= inv; probs8[t * 8 + e] = pr[e]; }
    int i0 = 0;
    for (int e = 1; e < E_NUM; ++e) if (pr[e] > pr[i0]) i0 = e;
    int i1 = (i0 == 0) ? 1 : 0;
    for (int e = 0; e < E_NUM; ++e) if (e != i0 && pr[e] > pr[i1]) i1 = e;
    float wsum = pr[i0] + pr[i1];
    topi[2 * t] = i0;  topi[2 * t + 1] = i1;
    topw[2 * t] = pr[i0] / wsum;  topw[2 * t + 1] = pr[i1] / wsum;
  }
}

// ---------------- histogram ----------------
__global__ void hist_k(const int* __restrict__ topi, const float* __restrict__ probs8,
                       int* __restrict__ cnt, float* __restrict__ usage) {
  __shared__ int sc[E_NUM];
  __shared__ float su[E_NUM];
  int tid = threadIdx.x;
  if (tid < E_NUM) { sc[tid] = 0; su[tid] = 0.f; }
  __syncthreads();
  for (int i = blockIdx.x * 256 + tid; i < 2 * T_TOK; i += 256 * 64)
    atomicAdd(&sc[topi[i]], 1);
  for (int i = blockIdx.x * 256 + tid; i < 8 * T_TOK; i += 256 * 64)
    atomicAdd(&su[i & 7], probs8[i]);
  __syncthreads();
  if (tid < E_NUM) { atomicAdd(&cnt[tid], sc[tid]); atomicAdd(&usage[tid], su[tid]); }
}

// ---------------- offsets (256-padded) + aux ----------------
__global__ void scan_k(const int* __restrict__ cnt, int* __restrict__ offs,
                       const float* __restrict__ usage, float* __restrict__ aux) {
  if (threadIdx.x == 0 && blockIdx.x == 0) {
    int o = 0;
    for (int e = 0; e < E_NUM; ++e) { offs[e] = o; o += (cnt[e] + 255) & ~255; }
    offs[E_NUM] = o;
    float s = 0.f;
    for (int e = 0; e < E_NUM; ++e) { float m = usage[e] * (1.f / T_TOK); s += m * m; }
    *aux = (float)E_NUM * s;
  }
}

// ---------------- assignment: pair -> row ----------------
__global__ void assign_k(const int* __restrict__ topi, const int* __restrict__ offs,
                         int* __restrict__ cur, int* __restrict__ rowpair) {
  int p = blockIdx.x * 256 + threadIdx.x;
  int lane = threadIdx.x & 63;
  int e = topi[p];
  int r = 0;
#pragma unroll
  for (int ee = 0; ee < E_NUM; ++ee) {
    unsigned long long mask = __ballot(e == ee);
    if (e == ee) {
      int leader = __ffsll((unsigned long long)mask) - 1;
      int rank = __popcll(mask & ((1ull << lane) - 1ull));
      int b = 0;
      if (lane == leader) b = atomicAdd(&cur[ee], (int)__popcll(mask));
      b = __shfl(b, leader);
      r = offs[ee] + b + rank;
    }
  }
  rowpair[r] = p;
}

// ====== reg-staged (T14) GEMM body: 128x128 tile, BK=64, 4 waves, 32KB LDS ======
// r9's proven 2-barrier loop; launch_bounds(256,3) -> 84 VGPR, no spill (verified).

#define RGEMM_BODY(NT, EPILOGUE)                                               \
  f32x4 acc[4][4] = {};                                                        \
  s16x8 rA[4], rB[4];                                                          \
  _Pragma("unroll") for (int i = 0; i < 4; ++i) {                              \
    rA[i] = *(const s16x8*)(pA[i]);                                            \
    rB[i] = *(const s16x8*)(pB[i]);                                            \
  }                                                                            \
  _Pragma("unroll 2")                                                          \
  for (int t = 0; t < NT; ++t) {                                               \
    if (t) __syncthreads();                                                    \
    _Pragma("unroll") for (int i = 0; i < 4; ++i) {                            \
      *(s16x8*)&As[wo[i]] = rA[i];                                             \
      *(s16x8*)&Bs[wo[i]] = rB[i];                                             \
    }                                                                          \
    __syncthreads();                                                           \
    if (t < NT - 1) {                                                          \
      int k0 = (t + 1) * 64;                                                   \
      _Pragma("unroll") for (int i = 0; i < 4; ++i) {                          \
        rA[i] = *(const s16x8*)(pA[i] + k0);                                   \
        rB[i] = *(const s16x8*)(pB[i] + k0);                                   \
      }                                                                        \
    }                                                                          \
    int ar = wm * 64 + rl, br = wn * 64 + rl;                                  \
    _Pragma("unroll") for (int kk = 0; kk < 2; ++kk) {                         \
      int cs = (((kk * 4 + g4) ^ (rl & 7)) << 3);                              \
      s16x8 a[4], b[4];                                                        \
      _Pragma("unroll") for (int m = 0; m < 4; ++m)                            \
        a[m] = *(const s16x8*)&As[(ar + m * 16) * 64 + cs];                    \
      _Pragma("unroll") for (int n = 0; n < 4; ++n)                            \
        b[n] = *(const s16x8*)&Bs[(br + n * 16) * 64 + cs];                    \
      __builtin_amdgcn_s_setprio(1);                                           \
      _Pragma("unroll") for (int m = 0; m < 4; ++m)                            \
        _Pragma("unroll") for (int n = 0; n < 4; ++n)                          \
          acc[m][n] = __builtin_amdgcn_mfma_f32_16x16x32_bf16(                 \
              a[m], b[n], acc[m][n], 0, 0, 0);                                 \
      __builtin_amdgcn_s_setprio(0);                                           \
    }                                                                          \
  }                                                                            \
  EPILOGUE

// ---------------- GEMM1: hseg = gelu(gather(xb) @ w1[e]^T) ----------------
__global__ __launch_bounds__(256, 3) void gemm1v_k(
    const unsigned short* __restrict__ xb, const unsigned short* __restrict__ w1b,
    const int* __restrict__ offs, const int* __restrict__ rowpair,
    const unsigned short* __restrict__ zrow,
    unsigned short* __restrict__ hseg, int segbase, int segrows) {
  int bid0 = blockIdx.x;
  int bid = ((bid0 & 7) << 11) | (bid0 >> 3);  // chunk swizzle (grid 16384)
  int e = bid >> 11, rem = bid & 2047, mt = rem >> 4, nt = rem & 15;
  int rend = offs[e + 1];
  int rowbase = offs[e] + mt * 128;
  if (rowbase >= rend || rowbase < segbase || rowbase >= segbase + segrows) return;

  __shared__ short As[128 * 64];
  __shared__ short Bs[128 * 64];
  int tid = threadIdx.x, wid = tid >> 6, lane = tid & 63;
  int wm = wid >> 1, wn = wid & 1, rl = lane & 15, g4 = lane >> 4;
  int j7 = tid & 7, rr = tid >> 3;  // rr 0..31
  int wg = ((j7 ^ (rr & 7)) << 3);
  int wo[4];
#pragma unroll
  for (int i = 0; i < 4; ++i) wo[i] = (rr + i * 32) * 64 + wg;

  const unsigned short* pA[4];
  const unsigned short* pB[4];
#pragma unroll
  for (int i = 0; i < 4; ++i) {
    int p = rowpair[rowbase + rr + i * 32];
    pA[i] = (p >= 0 ? xb + (size_t)(p >> 1) * D_DIM : zrow) + j7 * 8;
    pB[i] = w1b + ((size_t)e * F_DIM + nt * 128 + rr + i * 32) * D_DIM + j7 * 8;
  }

  RGEMM_BODY(16, {
    size_t rloc = (size_t)(rowbase - segbase);
    int c0 = nt * 128 + wn * 64 + rl;
    int lr0 = wm * 64 + (g4 << 2);
    _Pragma("unroll") for (int m = 0; m < 4; ++m)
      _Pragma("unroll") for (int j = 0; j < 4; ++j) {
        size_t rrow = (rloc + lr0 + m * 16 + j) * F_DIM;
        _Pragma("unroll") for (int n = 0; n < 4; ++n)
          hseg[rrow + c0 + n * 16] = f2b(gelu_f(acc[m][n][j]));
      }
  })
}

// ---------------- GEMM2 (store path): obuf[pair] = hseg @ w2[e]^T ----------------
__global__ __launch_bounds__(256, 3) void gemm2s_k(
    const unsigned short* __restrict__ hseg, const unsigned short* __restrict__ w2b,
    const int* __restrict__ offs, const int* __restrict__ rowpair,
    unsigned short* __restrict__ obuf, int segbase, int segrows) {
  int bid0 = blockIdx.x;
  int bid = ((bid0 & 7) << 10) | (bid0 >> 3);  // chunk swizzle (grid 8192)
  int e = bid >> 10, rem = bid & 1023, mt = rem >> 3, nt = rem & 7;
  int rend = offs[e + 1];
  int rowbase = offs[e] + mt * 128;
  if (rowbase >= rend || rowbase < segbase || rowbase >= segbase + segrows) return;

  __shared__ short As[128 * 64];
  __shared__ short Bs[128 * 64];
  int tid = threadIdx.x, wid = tid >> 6, lane = tid & 63;
  int wm = wid >> 1, wn = wid & 1, rl = lane & 15, g4 = lane >> 4;
  int j7 = tid & 7, rr = tid >> 3;
  int wg = ((j7 ^ (rr & 7)) << 3);
  int wo[4];
#pragma unroll
  for (int i = 0; i < 4; ++i) wo[i] = (rr + i * 32) * 64 + wg;

  size_t rloc = (size_t)(rowbase - segbase);
  const unsigned short* pA[4];
  const unsigned short* pB[4];
#pragma unroll
  for (int i = 0; i < 4; ++i) {
    pA[i] = hseg + (rloc + rr + i * 32) * F_DIM + j7 * 8;
    pB[i] = w2b + ((size_t)e * D_DIM + nt * 128 + rr + i * 32) * F_DIM + j7 * 8;
  }

  RGEMM_BODY(32, {
    int c0 = nt * 128 + wn * 64 + rl;
    int lr0 = wm * 64 + (g4 << 2);
    _Pragma("unroll") for (int m = 0; m < 4; ++m)
      _Pragma("unroll") for (int j = 0; j < 4; ++j) {
        int lr = lr0 + m * 16 + j;
        int p = rowpair[rowbase + lr];
        if (p >= 0) {
          unsigned short* op = obuf + (size_t)p * D_DIM + c0;
          _Pragma("unroll") for (int n = 0; n < 4; ++n)
            op[n * 16] = f2b(acc[m][n][j]);
        }
      }
  })
}

// ---------------- GEMM2 (atomic fallback, nseg>1) ----------------
__global__ __launch_bounds__(256, 3) void gemm2v_k(
    const unsigned short* __restrict__ hseg, const unsigned short* __restrict__ w2b,
    const int* __restrict__ offs, const int* __restrict__ rowpair,
    const float* __restrict__ topw, float* __restrict__ out,
    int segbase, int segrows) {
  int bid0 = blockIdx.x;
  int bid = ((bid0 & 7) << 10) | (bid0 >> 3);
  int e = bid >> 10, rem = bid & 1023, mt = rem >> 3, nt = rem & 7;
  int rend = offs[e + 1];
  int rowbase = offs[e] + mt * 128;
  if (rowbase >= rend || rowbase < segbase || rowbase >= segbase + segrows) return;

  __shared__ short As[128 * 64];
  __shared__ short Bs[128 * 64];
  int tid = threadIdx.x, wid = tid >> 6, lane = tid & 63;
  int wm = wid >> 1, wn = wid & 1, rl = lane & 15, g4 = lane >> 4;
  int j7 = tid & 7, rr = tid >> 3;
  int wg = ((j7 ^ (rr & 7)) << 3);
  int wo[4];
#pragma unroll
  for (int i = 0; i < 4; ++i) wo[i] = (rr + i * 32) * 64 + wg;

  size_t rloc = (size_t)(rowbase - segbase);
  const unsigned short* pA[4];
  const unsigned short* pB[4];
#pragma unroll
  for (int i = 0; i < 4; ++i) {
    pA[i] = hseg + (rloc + rr + i * 32) * F_DIM + j7 * 8;
    pB[i] = w2b + ((size_t)e * D_DIM + nt * 128 + rr + i * 32) * F_DIM + j7 * 8;
  }

  RGEMM_BODY(32, {
    int c0 = nt * 128 + wn * 64 + rl;
    int lr0 = wm * 64 + (g4 << 2);
    _Pragma("unroll") for (int m = 0; m < 4; ++m)
      _Pragma("unroll") for (int j = 0; j < 4; ++j) {
        int lr = lr0 + m * 16 + j;
        int p = rowpair[rowbase + lr];
        if (p >= 0) {
          float wgt = topw[p];
          float* op = out + (size_t)(p >> 1) * D_DIM + c0;
          _Pragma("unroll") for (int n = 0; n < 4; ++n)
            unsafeAtomicAdd(op + n * 16, wgt * acc[m][n][j]);
        }
      }
  })
}

// ---------------- combine: out[t] = w0*obuf[2t] + w1*obuf[2t+1] ----------------
__global__ void combine_k(const unsigned short* __restrict__ obuf,
                          const float* __restrict__ topw, float* __restrict__ out) {
  int u = blockIdx.x * 256 + threadIdx.x;
  int t = u >> 7;
  int d0 = (u & 127) * 8;
  float w0 = topw[2 * t], w1 = topw[2 * t + 1];
  s16x8 a = *(const s16x8*)(obuf + (size_t)(2 * t) * D_DIM + d0);
  s16x8 b = *(const s16x8*)(obuf + (size_t)(2 * t + 1) * D_DIM + d0);
  float r[8];
#pragma unroll
  for (int j = 0; j < 8; ++j)
    r[j] = w0 * b2f((unsigned short)a[j]) + w1 * b2f((unsigned short)b[j]);
  float4 lo = {r[0], r[1], r[2], r[3]};
  float4 hi = {r[4], r[5], r[6], r[7]};
  float* o = out + (size_t)t * D_DIM + d0;
  *(float4*)o = lo;
  *(float4*)(o + 4) = hi;
}

extern "C" void kernel_launch(void* const* d_in, const int* in_sizes, int n_in,
                              void* d_out, int out_size, void* d_ws, size_t ws_size,
                              hipStream_t stream) {
  const float* x  = (const float*)d_in[0];
  const float* wr = (const float*)d_in[1];
  const float* w1 = (const float*)d_in[2];
  const float* w2 = (const float*)d_in[3];
  float* out = (float*)d_out;

  char* ws = (char*)d_ws;
  int* cnt   = (int*)ws;               // [8]
  int* cur   = cnt + 8;                // [8]
  int* offs  = cnt + 16;               // [9]
  float* usage = (float*)(cnt + 25);   // [8]
  unsigned short* zrow = (unsigned short*)(ws + 4096);  // 2KB zeros (= D_DIM bf16)
  size_t off = 8192;
  int*   topi = (int*)(ws + off);     off += (size_t)2 * T_TOK * 4;
  float* topw = (float*)(ws + off);   off += (size_t)2 * T_TOK * 4;
  int*   rowpair = (int*)(ws + off);  off += (size_t)RCAP * 4;
  float* probs8 = (float*)(ws + off); off += (size_t)T_TOK * 8 * 4;
  off = (off + 255) & ~(size_t)255;

  unsigned short* xb = (unsigned short*)(ws + off);
  off += (size_t)T_TOK * D_DIM * 2;                       // 33.6 MB
  unsigned short* w1b = (unsigned short*)(ws + off);
  off += (size_t)E_NUM * F_DIM * D_DIM * 2;               // 33.6 MB
  unsigned short* w2b = (unsigned short*)(ws + off);
  off += (size_t)E_NUM * F_DIM * D_DIM * 2;               // 33.6 MB
  if (ws_size < off + (size_t)4096 * F_DIM * 2) return;   // need >= 16.8MB hseg
  size_t avail = ws_size - off;
  size_t segcap = (avail / ((size_t)F_DIM * 2)) & ~(size_t)255;
  int segrows = segcap > (size_t)RCAP ? RCAP : (int)segcap;
  unsigned short* hseg = (unsigned short*)(ws + off);
  int nseg = (RCAP + segrows - 1) / segrows;

  // Store path: obuf[pair] (2*T rows, 67.1MB) aliases xb+w1b (67.2MB) — safe
  // only when nseg==1 (gemm1 fully done with xb/w1b before gemm2 writes).
  bool storepath = (nseg == 1);
  unsigned short* obuf = xb;

  hipMemsetAsync(ws, 0, 8192, stream);
  hipMemsetAsync(rowpair, 0xFF, (size_t)RCAP * 4, stream);
  if (!storepath) hipMemsetAsync(d_out, 0, (size_t)out_size * 4, stream);
  castw_k<<<16384, 256, 0, stream>>>(w1, w2, w1b, w2b);
  router_k<<<T_TOK / 4, 256, 0, stream>>>(x, wr, topi, topw, probs8, xb);
  hist_k<<<64, 256, 0, stream>>>(topi, probs8, cnt, usage);
  scan_k<<<1, 64, 0, stream>>>(cnt, offs, usage, out + (size_t)T_TOK * D_DIM);
  assign_k<<<2 * T_TOK / 256, 256, 0, stream>>>(topi, offs, cur, rowpair);

  for (int s = 0; s < nseg; ++s) {
    int segbase = s * segrows;
    gemm1v_k<<<16384, 256, 0, stream>>>(xb, w1b, offs, rowpair, zrow, hseg, segbase, segrows);
    if (storepath)
      gemm2s_k<<<8192, 256, 0, stream>>>(hseg, w2b, offs, rowpair, obuf, segbase, segrows);
    else
      gemm2v_k<<<8192, 256, 0, stream>>>(hseg, w2b, offs, rowpair, topw, out, segbase, segrows);
  }
  if (storepath)
    combine_k<<<T_TOK * D_DIM / 8 / 256, 256, 0, stream>>>(obuf, topw, out);
}